// Round 14
// baseline (205.680 us; speedup 1.0000x reference)
//
#include <hip/hip_runtime.h>
#include <hip/hip_bf16.h>

// GCN 2-layer. Bucketized padded-CSR build + per-bucket degree-sorted node
// permutation (aggA/aggB process dsts in perm order -> minimal wave divergence).
// Pre-scaled bf16 intermediates (h1s = h1*dinv), MFMA linear1 (grid-saturated),
// linear2 FUSED into aggA (LDS act tile + wave-0 MFMA -> h2s).
// flags[0]=1 if floats bf16 else fp32; flags[1]=1 if edge_index int64 else int32.

constexpr int D_IN  = 128;
constexpr int D_HID = 64;
constexpr int D_OUT = 16;

constexpr int WSHIFT  = 9;       // bucket = dst >> 9 (512 nodes/bucket)
constexpr int MAXB    = 256;     // max buckets (n <= 131072)
constexpr int BCAP    = 12288;   // gbuf bucket capacity (mean ~8163 at E/N=16)
constexpr int CSRCAP  = 16384;   // csr bucket region (BCAP + 512*8 padding)
constexpr int BIN_CAP = 48;      // LDS bin cap per bucket per chunk (mean ~21)
constexpr int CHUNK   = 4096;

typedef __attribute__((ext_vector_type(8))) short bf16x8;
typedef __attribute__((ext_vector_type(4))) float f32x4;

__device__ inline float bflo(unsigned u){ return __uint_as_float(u << 16); }
__device__ inline float bfhi(unsigned u){ return __uint_as_float(u & 0xffff0000u); }
__device__ inline unsigned f2bu(float f){
    __hip_bfloat16 h = __float2bfloat16(f);
    return (unsigned)*reinterpret_cast<unsigned short*>(&h);
}
__device__ inline float sigf(float x){ return 1.0f / (1.0f + __expf(-x)); }

// ---------------- phase 1: bucketize edges by dst>>9 + on-device dtype detect ----------------
__global__ __launch_bounds__(256) void k_bucketize(
    const int* __restrict__ ei, const unsigned* __restrict__ xraw,
    int* __restrict__ flags, unsigned* __restrict__ gcur,
    unsigned* __restrict__ gbuf, int ne, int B)
{
    __shared__ unsigned bcnt[MAXB];
    __shared__ unsigned bbase[MAXB];
    __shared__ unsigned bins[MAXB * BIN_CAP];   // 49 KB
    __shared__ int s_i64;

    const int t = threadIdx.x, lane = t & 63, wv = t >> 6;
    const int e0 = blockIdx.x * CHUNK;

    if (t < MAXB) bcnt[t] = 0u;
    if (wv == 0){
        int w = ei[2 * lane + 1];
        unsigned long long m = __ballot(w == 0);
        if (lane == 0) s_i64 = (__popcll(m) > 48) ? 1 : 0;
        if (blockIdx.x == 0){
            unsigned u = xraw[lane];
            unsigned h0 = u & 0xffffu, h1 = u >> 16;
            unsigned ex0 = (h0 >> 7) & 0xffu, ex1 = (h1 >> 7) & 0xffu;
            bool bad0 = !((h0 & 0x7fffu) == 0 || (ex0 >= 97 && ex0 <= 157));
            bool bad1 = !((h1 & 0x7fffu) == 0 || (ex1 >= 97 && ex1 <= 157));
            unsigned long long m0 = __ballot(bad0);
            unsigned long long m1 = __ballot(bad1);
            if (lane == 0){
                int bad = __popcll(m0) + __popcll(m1);
                flags[0] = (bad > 8) ? 0 : 1;
                flags[1] = s_i64;
            }
        }
    }
    __syncthreads();
    const int i64 = s_i64;
    const bool vec = ((ne & 1) == 0);

    #pragma unroll
    for (int k = 0; k < CHUNK / 512; ++k){
        int e = e0 + k * 512 + 2 * t;
        int s0, d0, s1, d1;
        int cntE = 0;
        if (vec && e < ne){
            if (i64){
                int4 sp = *(const int4*)&ei[2 * e];
                int4 dp = *(const int4*)&ei[2 * (ne + e)];
                s0 = sp.x; s1 = sp.z; d0 = dp.x; d1 = dp.z;
            } else {
                int2 sp = *(const int2*)&ei[e];
                int2 dp = *(const int2*)&ei[ne + e];
                s0 = sp.x; s1 = sp.y; d0 = dp.x; d1 = dp.y;
            }
            cntE = 2;
        } else {
            if (e < ne){
                if (i64){ s0 = ei[2*e]; d0 = ei[2*(ne+e)]; }
                else    { s0 = ei[e];   d0 = ei[ne+e]; }
                cntE = 1;
                if (e + 1 < ne){
                    if (i64){ s1 = ei[2*(e+1)]; d1 = ei[2*(ne+e+1)]; }
                    else    { s1 = ei[e+1];     d1 = ei[ne+e+1]; }
                    cntE = 2;
                }
            }
        }
        #pragma unroll
        for (int j = 0; j < 2; ++j){
            if (j < cntE){
                int s = j ? s1 : s0, d = j ? d1 : d0;
                int b = d >> WSHIFT;
                unsigned v = ((unsigned)s << WSHIFT) | ((unsigned)d & ((1u << WSHIFT) - 1));
                unsigned p = atomicAdd(&bcnt[b], 1u);
                if (p < (unsigned)BIN_CAP){
                    bins[b * BIN_CAP + p] = v;
                } else {
                    unsigned g = atomicAdd(&gcur[b], 1u);
                    gbuf[(size_t)b * BCAP + g] = v;
                }
            }
        }
    }
    __syncthreads();

    if (t < B){
        unsigned c = min(bcnt[t], (unsigned)BIN_CAP);
        bbase[t] = atomicAdd(&gcur[t], c);
    }
    __syncthreads();

    for (int b = wv; b < B; b += 4){
        unsigned c = min(bcnt[b], (unsigned)BIN_CAP);
        for (unsigned o = lane; o < c; o += 64)
            gbuf[(size_t)b * BCAP + bbase[b] + o] = bins[b * BIN_CAP + o];
    }
}

// ---------------- phase 2: per-bucket hist + scan + PADDED csr fill + degree sort ----------------
__global__ __launch_bounds__(1024) void k_build(
    const unsigned* __restrict__ gbuf, const unsigned* __restrict__ gcnt,
    unsigned* __restrict__ off, unsigned* __restrict__ offend,
    float* __restrict__ dinv, int* __restrict__ csr, unsigned* __restrict__ perm,
    int n, int B)
{
    __shared__ unsigned hist[512];
    __shared__ unsigned offl[512];
    __shared__ unsigned wsums[8];
    __shared__ unsigned ccnt[64];
    __shared__ unsigned cbase[64];

    const int t = threadIdx.x, lane = t & 63, wv = t >> 6;
    const int b = blockIdx.x;
    const int base = b << WSHIFT;
    const int nodes = min(512, n - base);
    const unsigned bb = (unsigned)b * CSRCAP;

    if (t < 512) hist[t] = 0u;
    if (t < 64)  ccnt[t] = 0u;
    __syncthreads();
    const unsigned cnt = gcnt[b];
    const unsigned* mybuf = gbuf + (size_t)b * BCAP;

    for (unsigned i = t; i < cnt; i += 1024)
        atomicAdd(&hist[mybuf[i] & ((1u << WSHIFT) - 1)], 1u);
    __syncthreads();

    unsigned v = 0, p = 0, x = 0;
    if (t < 512){
        v = hist[t];
        p = (v + 7u) & ~7u;
        x = p;
        #pragma unroll
        for (int o = 1; o < 64; o <<= 1){
            unsigned y = __shfl_up(x, o, 64);
            if (lane >= o) x += y;
        }
        if (lane == 63) wsums[wv] = x;
    }
    __syncthreads();
    if (t == 0){
        unsigned run = 0;
        #pragma unroll
        for (int w = 0; w < 8; ++w){ unsigned tv = wsums[w]; wsums[w] = run; run += tv; }
    }
    __syncthreads();
    if (t < 512) offl[t] = x - p + wsums[wv];
    __syncthreads();

    if (t < nodes){
        off[base + t]    = bb + offl[t];
        offend[base + t] = bb + offl[t] + p;
        dinv[base + t]   = rsqrtf(1.0f + (float)v);
    }
    __syncthreads();

    if (t < 512) hist[t] = offl[t];
    __syncthreads();

    for (unsigned i = t; i < cnt; i += 1024){
        unsigned rec = mybuf[i];
        unsigned pos = atomicAdd(&hist[rec & ((1u << WSHIFT) - 1)], 1u);
        csr[bb + pos] = (int)(rec >> WSHIFT);
    }
    __syncthreads();

    if (t < nodes){
        unsigned s = offl[t] + v, e2 = offl[t] + p;
        for (unsigned j = s; j < e2; ++j) csr[bb + j] = n;
    }

    // degree-class counting sort -> perm (bucket-local)
    const unsigned cls = min(p >> 3, 63u);
    if (t < nodes) atomicAdd(&ccnt[cls], 1u);
    __syncthreads();
    if (t == 0){
        unsigned run = 0;
        #pragma unroll
        for (int i = 0; i < 64; ++i){ unsigned tv = ccnt[i]; cbase[i] = run; run += tv; }
    }
    __syncthreads();
    if (t < 64) ccnt[t] = cbase[t];
    __syncthreads();
    if (t < nodes){
        unsigned r = atomicAdd(&ccnt[cls], 1u);
        perm[base + r] = (unsigned)(base + t);
    }
}

// ---------------- linear 1 (MFMA): h1s(bf16) = (x @ W1) * dinv[node]; row n = 0 ----------------
__global__ __launch_bounds__(256) void k_linear1(
    const unsigned* __restrict__ xraw, const unsigned* __restrict__ w1raw,
    const int* __restrict__ flags, const float* __restrict__ dinv,
    unsigned short* __restrict__ h1s, int n)
{
    const int lane = threadIdx.x & 63;
    const int wv   = threadIdx.x >> 6;
    const int m = lane & 15, q = lane >> 4;
    const int isBf16 = flags[0];

    if (blockIdx.x == 0 && threadIdx.x < 16)
        ((uint2*)(h1s + (size_t)n * D_HID))[threadIdx.x] = make_uint2(0u, 0u);

    bf16x8 bfr[4][4];
    if (isBf16){
        const unsigned short* w = (const unsigned short*)w1raw;
        #pragma unroll
        for (int kc = 0; kc < 4; ++kc)
            #pragma unroll
            for (int ct = 0; ct < 4; ++ct)
                #pragma unroll
                for (int j = 0; j < 8; ++j)
                    bfr[kc][ct][j] = (short)w[(kc*32 + q*8 + j) * D_HID + ct*16 + m];
    } else {
        const float* w = (const float*)w1raw;
        #pragma unroll
        for (int kc = 0; kc < 4; ++kc)
            #pragma unroll
            for (int ct = 0; ct < 4; ++ct)
                #pragma unroll
                for (int j = 0; j < 8; ++j)
                    bfr[kc][ct][j] = (short)f2bu(w[(kc*32 + q*8 + j) * D_HID + ct*16 + m]);
    }

    const int ntiles = (n + 15) >> 4;
    for (int tile = blockIdx.x * 4 + wv; tile < ntiles; tile += gridDim.x * 4){
        const int node0 = tile << 4;
        int arow = node0 + m; if (arow >= n) arow = n - 1;
        f32x4 ac0 = {0,0,0,0}, ac1 = {0,0,0,0}, ac2 = {0,0,0,0}, ac3 = {0,0,0,0};
        #pragma unroll
        for (int kc = 0; kc < 4; ++kc){
            bf16x8 a;
            if (isBf16){
                uint4 u = *(const uint4*)((const unsigned short*)xraw + (size_t)arow * D_IN + kc*32 + q*8);
                a = *reinterpret_cast<bf16x8*>(&u);
            } else {
                const float* xp = (const float*)xraw + (size_t)arow * D_IN + kc*32 + q*8;
                float4 f0 = *(const float4*)xp;
                float4 f1 = *(const float4*)(xp + 4);
                a[0]=(short)f2bu(f0.x); a[1]=(short)f2bu(f0.y); a[2]=(short)f2bu(f0.z); a[3]=(short)f2bu(f0.w);
                a[4]=(short)f2bu(f1.x); a[5]=(short)f2bu(f1.y); a[6]=(short)f2bu(f1.z); a[7]=(short)f2bu(f1.w);
            }
            ac0 = __builtin_amdgcn_mfma_f32_16x16x32_bf16(a, bfr[kc][0], ac0, 0, 0, 0);
            ac1 = __builtin_amdgcn_mfma_f32_16x16x32_bf16(a, bfr[kc][1], ac1, 0, 0, 0);
            ac2 = __builtin_amdgcn_mfma_f32_16x16x32_bf16(a, bfr[kc][2], ac2, 0, 0, 0);
            ac3 = __builtin_amdgcn_mfma_f32_16x16x32_bf16(a, bfr[kc][3], ac3, 0, 0, 0);
        }
        #pragma unroll
        for (int i = 0; i < 4; ++i){
            int nr = node0 + q*4 + i;
            if (nr < n){
                float di = dinv[nr];
                unsigned short* o = h1s + (size_t)nr * D_HID + m;
                o[0]  = (unsigned short)f2bu(ac0[i] * di);
                o[16] = (unsigned short)f2bu(ac1[i] * di);
                o[32] = (unsigned short)f2bu(ac2[i] * di);
                o[48] = (unsigned short)f2bu(ac3[i] * di);
            }
        }
    }
}

// ---------------- aggA + fused linear2, perm-ordered ----------------
__global__ __launch_bounds__(256) void k_aggA(
    const unsigned* __restrict__ off, const unsigned* __restrict__ offend,
    const int* __restrict__ csr_src, const unsigned* __restrict__ perm,
    const float* __restrict__ dinv, const unsigned short* __restrict__ h1s,
    const unsigned* __restrict__ b1raw, const unsigned* __restrict__ w2raw,
    const int* __restrict__ flags,
    unsigned short* __restrict__ h2s, int n)
{
    __shared__ unsigned short act_s[16][72];   // 16-node act tile, padded

    const int lane = threadIdx.x & 63;
    const int wv   = threadIdx.x >> 6;
    const int grp  = lane >> 4;            // dst within wave (0..3)
    const int f    = lane & 15;            // uint2 index within 64-feature row
    const int dl   = wv * 4 + grp;         // dst within block (0..15)
    const int idx  = blockIdx.x * 16 + dl; // perm index
    const int isBf16 = flags[0];

    bf16x8 w2f[2];
    if (wv == 0){
        const int m0 = lane & 15, q0 = lane >> 4;
        if (isBf16){
            const unsigned short* w = (const unsigned short*)w2raw;
            #pragma unroll
            for (int kc = 0; kc < 2; ++kc)
                #pragma unroll
                for (int j = 0; j < 8; ++j)
                    w2f[kc][j] = (short)w[(kc*32 + q0*8 + j) * D_OUT + m0];
        } else {
            const float* w = (const float*)w2raw;
            #pragma unroll
            for (int kc = 0; kc < 2; ++kc)
                #pragma unroll
                for (int j = 0; j < 8; ++j)
                    w2f[kc][j] = (short)f2bu(w[(kc*32 + q0*8 + j) * D_OUT + m0]);
        }
        if (blockIdx.x == 0 && lane < 4)
            ((uint2*)(h2s + (size_t)n * D_OUT))[lane] = make_uint2(0u, 0u);
    }

    if (idx < n){
        const int d = (int)perm[idx];
        const int beg = (int)off[d], end = (int)offend[d];
        float a0=0.f, a1=0.f, a2=0.f, a3=0.f;
        for (int i = beg; i < end; i += 8){
            uint4 cA = *(const uint4*)&csr_src[i];
            uint4 cB = *(const uint4*)&csr_src[i + 4];
            uint2 u0 = *(const uint2*)&h1s[(size_t)(unsigned)cA.x * D_HID + f * 4];
            uint2 u1 = *(const uint2*)&h1s[(size_t)(unsigned)cA.y * D_HID + f * 4];
            uint2 u2 = *(const uint2*)&h1s[(size_t)(unsigned)cA.z * D_HID + f * 4];
            uint2 u3 = *(const uint2*)&h1s[(size_t)(unsigned)cA.w * D_HID + f * 4];
            uint2 u4 = *(const uint2*)&h1s[(size_t)(unsigned)cB.x * D_HID + f * 4];
            uint2 u5 = *(const uint2*)&h1s[(size_t)(unsigned)cB.y * D_HID + f * 4];
            uint2 u6 = *(const uint2*)&h1s[(size_t)(unsigned)cB.z * D_HID + f * 4];
            uint2 u7 = *(const uint2*)&h1s[(size_t)(unsigned)cB.w * D_HID + f * 4];
            a0 += bflo(u0.x) + bflo(u1.x) + bflo(u2.x) + bflo(u3.x)
                + bflo(u4.x) + bflo(u5.x) + bflo(u6.x) + bflo(u7.x);
            a1 += bfhi(u0.x) + bfhi(u1.x) + bfhi(u2.x) + bfhi(u3.x)
                + bfhi(u4.x) + bfhi(u5.x) + bfhi(u6.x) + bfhi(u7.x);
            a2 += bflo(u0.y) + bflo(u1.y) + bflo(u2.y) + bflo(u3.y)
                + bflo(u4.y) + bflo(u5.y) + bflo(u6.y) + bflo(u7.y);
            a3 += bfhi(u0.y) + bfhi(u1.y) + bfhi(u2.y) + bfhi(u3.y)
                + bfhi(u4.y) + bfhi(u5.y) + bfhi(u6.y) + bfhi(u7.y);
        }
        uint2 su = *(const uint2*)&h1s[(size_t)d * D_HID + f * 4];
        a0 += bflo(su.x); a1 += bfhi(su.x);
        a2 += bflo(su.y); a3 += bfhi(su.y);
        const float dd = dinv[d];
        float b0, b1v, b2v, b3v;
        if (isBf16){
            uint2 bu = ((const uint2*)b1raw)[f];
            b0 = bflo(bu.x); b1v = bfhi(bu.x); b2v = bflo(bu.y); b3v = bfhi(bu.y);
        } else {
            float4 bb = ((const float4*)b1raw)[f];
            b0 = bb.x; b1v = bb.y; b2v = bb.z; b3v = bb.w;
        }
        act_s[dl][f*4+0] = (unsigned short)f2bu(sigf(fmaf(a0, dd, b0)));
        act_s[dl][f*4+1] = (unsigned short)f2bu(sigf(fmaf(a1, dd, b1v)));
        act_s[dl][f*4+2] = (unsigned short)f2bu(sigf(fmaf(a2, dd, b2v)));
        act_s[dl][f*4+3] = (unsigned short)f2bu(sigf(fmaf(a3, dd, b3v)));
    } else {
        #pragma unroll
        for (int j = 0; j < 4; ++j) act_s[dl][f*4+j] = 0;
    }
    __syncthreads();

    if (wv == 0){
        const int m0 = lane & 15, q0 = lane >> 4;
        f32x4 acc = {0,0,0,0};
        #pragma unroll
        for (int kc = 0; kc < 2; ++kc){
            bf16x8 a;
            #pragma unroll
            for (int j = 0; j < 8; ++j)
                a[j] = (short)act_s[m0][kc*32 + q0*8 + j];
            acc = __builtin_amdgcn_mfma_f32_16x16x32_bf16(a, w2f[kc], acc, 0, 0, 0);
        }
        #pragma unroll
        for (int i = 0; i < 4; ++i){
            int pidx = blockIdx.x * 16 + q0*4 + i;
            if (pidx < n){
                int nr = (int)perm[pidx];
                h2s[(size_t)nr * D_OUT + m0] = (unsigned short)f2bu(acc[i] * dinv[nr]);
            }
        }
    }
}

// ---------------- aggB: perm-ordered, 16 dst/wave, 4 lanes/dst, unroll x8 ----------------
__global__ __launch_bounds__(256) void k_aggB(
    const unsigned* __restrict__ off, const unsigned* __restrict__ offend,
    const int* __restrict__ csr_src, const unsigned* __restrict__ perm,
    const float* __restrict__ dinv, const unsigned short* __restrict__ h2s,
    const unsigned* __restrict__ b2raw, const int* __restrict__ flags,
    void* __restrict__ out, int n)
{
    const int lane = threadIdx.x & 63;
    const int wv   = threadIdx.x >> 6;
    const int grp  = lane >> 2;            // dst within wave (0..15)
    const int f    = lane & 3;             // uint2 index within 16-feature row
    const int idx  = (blockIdx.x * 4 + wv) * 16 + grp;
    const int isBf16 = flags[0];
    if (idx >= n) return;
    const int d = (int)perm[idx];

    const int beg = (int)off[d], end = (int)offend[d];
    float a0=0.f, a1=0.f, a2=0.f, a3=0.f;
    for (int i = beg; i < end; i += 8){
        uint4 cA = *(const uint4*)&csr_src[i];
        uint4 cB = *(const uint4*)&csr_src[i + 4];
        uint2 u0 = *(const uint2*)&h2s[(size_t)(unsigned)cA.x * D_OUT + f * 4];
        uint2 u1 = *(const uint2*)&h2s[(size_t)(unsigned)cA.y * D_OUT + f * 4];
        uint2 u2 = *(const uint2*)&h2s[(size_t)(unsigned)cA.z * D_OUT + f * 4];
        uint2 u3 = *(const uint2*)&h2s[(size_t)(unsigned)cA.w * D_OUT + f * 4];
        uint2 u4 = *(const uint2*)&h2s[(size_t)(unsigned)cB.x * D_OUT + f * 4];
        uint2 u5 = *(const uint2*)&h2s[(size_t)(unsigned)cB.y * D_OUT + f * 4];
        uint2 u6 = *(const uint2*)&h2s[(size_t)(unsigned)cB.z * D_OUT + f * 4];
        uint2 u7 = *(const uint2*)&h2s[(size_t)(unsigned)cB.w * D_OUT + f * 4];
        a0 += bflo(u0.x) + bflo(u1.x) + bflo(u2.x) + bflo(u3.x)
            + bflo(u4.x) + bflo(u5.x) + bflo(u6.x) + bflo(u7.x);
        a1 += bfhi(u0.x) + bfhi(u1.x) + bfhi(u2.x) + bfhi(u3.x)
            + bfhi(u4.x) + bfhi(u5.x) + bfhi(u6.x) + bfhi(u7.x);
        a2 += bflo(u0.y) + bflo(u1.y) + bflo(u2.y) + bflo(u3.y)
            + bflo(u4.y) + bflo(u5.y) + bflo(u6.y) + bflo(u7.y);
        a3 += bfhi(u0.y) + bfhi(u1.y) + bfhi(u2.y) + bfhi(u3.y)
            + bfhi(u4.y) + bfhi(u5.y) + bfhi(u6.y) + bfhi(u7.y);
    }
    uint2 su = *(const uint2*)&h2s[(size_t)d * D_OUT + f * 4];
    a0 += bflo(su.x); a1 += bfhi(su.x);
    a2 += bflo(su.y); a3 += bfhi(su.y);
    const float dd = dinv[d];
    float b0, b1v, b2v, b3v;
    if (isBf16){
        uint2 bu = ((const uint2*)b2raw)[f];
        b0 = bflo(bu.x); b1v = bfhi(bu.x); b2v = bflo(bu.y); b3v = bfhi(bu.y);
    } else {
        float4 bb = ((const float4*)b2raw)[f];
        b0 = bb.x; b1v = bb.y; b2v = bb.z; b3v = bb.w;
    }
    a0 = fmaf(a0, dd, b0); a1 = fmaf(a1, dd, b1v);
    a2 = fmaf(a2, dd, b2v); a3 = fmaf(a3, dd, b3v);
    float m = fmaxf(fmaxf(a0, a1), fmaxf(a2, a3));
    m = fmaxf(m, __shfl_xor(m, 1, 4));
    m = fmaxf(m, __shfl_xor(m, 2, 4));
    float s = __expf(a0 - m) + __expf(a1 - m) + __expf(a2 - m) + __expf(a3 - m);
    s += __shfl_xor(s, 1, 4);
    s += __shfl_xor(s, 2, 4);
    float ls = m + __logf(s);
    if (isBf16){
        uint2 pk;
        pk.x = f2bu(a0 - ls) | (f2bu(a1 - ls) << 16);
        pk.y = f2bu(a2 - ls) | (f2bu(a3 - ls) << 16);
        *(uint2*)((__hip_bfloat16*)out + (size_t)d * D_OUT + f * 4) = pk;
    } else {
        float4 o4 = make_float4(a0 - ls, a1 - ls, a2 - ls, a3 - ls);
        *(float4*)((float*)out + (size_t)d * D_OUT + f * 4) = o4;
    }
}

extern "C" void kernel_launch(void* const* d_in, const int* in_sizes, int n_in,
                              void* d_out, int out_size, void* d_ws, size_t ws_size,
                              hipStream_t stream)
{
    const unsigned* xraw  = (const unsigned*)d_in[0];
    const int*      ei    = (const int*)d_in[1];
    const unsigned* w1raw = (const unsigned*)d_in[2];
    const unsigned* b1raw = (const unsigned*)d_in[3];
    const unsigned* w2raw = (const unsigned*)d_in[4];
    const unsigned* b2raw = (const unsigned*)d_in[5];

    const int n  = in_sizes[0] / D_IN;   // 100000
    const int ne = in_sizes[1] / 2;      // 1600000
    const int B  = (n + ((1 << WSHIFT) - 1)) >> WSHIFT;   // 196 buckets

    // ws layout (4B words):
    // flags[64] | gcur[256] | dinv[nAl] | off[nAl] | offend[nAl] | perm[nAl]
    //   | csr[MAXB*CSRCAP] | gbuf[MAXB*BCAP] | h1s[(n+16)*64 bf16] | h2s[(n+16)*16 bf16]
    size_t nAl = ((size_t)n + 255) & ~(size_t)255;
    int*            flags  = (int*)d_ws;
    unsigned*       gcur   = (unsigned*)d_ws + 64;
    float*          dinv   = (float*)(gcur + 256);
    unsigned*       off    = (unsigned*)(dinv + nAl);
    unsigned*       offend = off + nAl;
    unsigned*       perm   = offend + nAl;
    int*            csr    = (int*)(perm + nAl);
    unsigned*       gbuf   = (unsigned*)(csr + (size_t)MAXB * CSRCAP);
    unsigned short* h1s    = (unsigned short*)(gbuf + (size_t)MAXB * BCAP);
    unsigned short* h2s    = h1s + (size_t)(n + 16) * D_HID;

    const int nchunk  = (ne + CHUNK - 1) / CHUNK;
    const int ntiles1 = (n + 15) / 16;
    const int grid1   = (ntiles1 + 3) / 4;    // one 16-node tile per wave

    hipMemsetAsync(gcur, 0, MAXB * sizeof(unsigned), stream);
    k_bucketize <<<nchunk, 256, 0, stream>>>(ei, xraw, flags, gcur, gbuf, ne, B);
    k_build     <<<B, 1024, 0, stream>>>(gbuf, gcur, off, offend, dinv, csr, perm, n, B);

    k_linear1   <<<grid1, 256, 0, stream>>>(xraw, w1raw, flags, dinv, h1s, n);
    k_aggA      <<<(n + 15) / 16, 256, 0, stream>>>(off, offend, csr, perm, dinv, h1s, b1raw, w2raw, flags, h2s, n);
    k_aggB      <<<(n + 63) / 64, 256, 0, stream>>>(off, offend, csr, perm, dinv, h2s, b2raw, flags, d_out, n);
}